// Round 1
// baseline (48.329 us; speedup 1.0000x reference)
//
#include <hip/hip_runtime.h>
#include <stdint.h>

// Soft decision-tree ensemble, collapsed:
//   out[b,c] = sum_t ( A'[t,c] + sum_{k<4} d[b,t,k]*B'[t,k,c] ) / (4 + d[b,t,3] + 1e-8)
//   d[b,t,k] = sigmoid( X[b,:] . W[t,k,:] + bias[t,k] ),  only internal nodes 0..3 used.
// GEMM: 65536 x 512 @ 512 x 256 (fp16 MFMA), memory-bound on X (128 MiB fp32).

#define BATCH 65536
#define KDIM 512
#define NCOL 256          // 64 trees * 4 nodes
#define PPT 3607

typedef _Float16 f16x8 __attribute__((ext_vector_type(8)));
typedef float f32x4 __attribute__((ext_vector_type(4)));

// ws layout (bytes):
//   [0, 262144)       Wh   : _Float16 [256 cols][512 k]   (col = t*4+k_node)
//   [262144, 263168)  biasN: float[256]
//   [263168, 265728)  AB   : float[64][10]  (A'c0,A'c1, B'k0c0,B'k0c1, ... B'k3c1), w_t folded

__global__ __launch_bounds__(128) void prep_kernel(const float* __restrict__ p,
                                                   const float* __restrict__ tw,
                                                   _Float16* __restrict__ Wh,
                                                   float* __restrict__ biasN,
                                                   float* __restrict__ AB) {
    const int c = blockIdx.x;          // 0..255
    const int t = c >> 2, i = c & 3;
    const float* wsrc = p + t * PPT + i * KDIM;
    for (int k = threadIdx.x; k < KDIM; k += 128)
        Wh[c * KDIM + k] = (_Float16)wsrc[k];
    if (threadIdx.x == 0)
        biasN[c] = p[t * PPT + 7 * KDIM + i];
    if (threadIdx.x == 64 && c < 64) {
        const int tt = c;
        const float* lg = p + tt * PPT + 7 * 513;   // leaf logits, 8 x 2
        const float w = tw[tt];
        float ld[8][2];
#pragma unroll
        for (int j = 0; j < 8; ++j) {
            float a = lg[2 * j], b = lg[2 * j + 1];
            float m = fmaxf(a, b);
            float e0 = expf(a - m), e1 = expf(b - m);
            float s = e0 + e1;
            ld[j][0] = e0 / s; ld[j][1] = e1 / s;
        }
        float* o = AB + tt * 10;
#pragma unroll
        for (int cc = 0; cc < 2; ++cc) {
            o[0 + cc] = w * (ld[0][cc] + ld[2][cc] + ld[4][cc] + ld[6][cc]);
            o[2 + cc] = w * (ld[1][cc] - ld[2][cc]);
            o[4 + cc] = w * (ld[3][cc] - ld[4][cc]);
            o[6 + cc] = w * (ld[5][cc] - ld[6][cc]);
            o[8 + cc] = w * (ld[7][cc]);
        }
    }
}

// LDS map (dynamic, 138240 B):
//   staging (halves): buf b at b*32768;  A: [256 rows][64 k] at +0, B: [256 cols][64 k] at +16384
//                     swizzle: halfidx = row*64 + (k ^ ((row&7)<<3))
//   epilogue (floats): d_lds [128][257] at 0;  partials [4][128][2] at 32896;  AB copy at 33920 (640 f)
#define AB_LDS 33920
#define PART_LDS 32896

__global__ __launch_bounds__(512, 2) void main_kernel(const float* __restrict__ X,
                                                      const _Float16* __restrict__ Wh,
                                                      const float* __restrict__ biasN,
                                                      const float* __restrict__ ABg,
                                                      float* __restrict__ out) {
    extern __shared__ char smem[];
    _Float16* lds_h = (_Float16*)smem;
    float* lds_f = (float*)smem;

    const int tid = threadIdx.x;
    const int lane = tid & 63;
    const int wid = tid >> 6;
    const int wm = wid >> 2;          // 0..1 : 128-row half
    const int wn = wid & 3;           // 0..3 : 64-col quarter
    const int gr0 = blockIdx.x * 256; // 256 rows per block

    // preload folded leaf coefficients into LDS (own region, read only in epilogue)
#pragma unroll
    for (int i = 0; i < 2; ++i) {
        int idx = tid + i * 512;
        if (idx < 640) lds_f[AB_LDS + idx] = ABg[idx];
    }

    f32x4 acc[8][4];
#pragma unroll
    for (int rt = 0; rt < 8; ++rt)
#pragma unroll
        for (int nt = 0; nt < 4; ++nt)
            acc[rt][nt] = (f32x4){0.f, 0.f, 0.f, 0.f};

    // staging assignment: this thread owns (row=arow, k-half=akq..akq+31) of both A and B tiles
    const int arow = tid >> 1;            // 0..255
    const int akq = (tid & 1) * 32;       // 0 or 32
    const int sw = (arow & 7) << 3;       // swizzle term
    const float* Xrow = X + (size_t)(gr0 + arow) * KDIM + akq;
    const _Float16* Wrow = Wh + (size_t)arow * KDIM + akq;

    float4 ar[8];
    uint4 br[4];

    // ---- prologue: stage kt=0 into buf 0
#pragma unroll
    for (int j = 0; j < 8; ++j) ar[j] = *(const float4*)(Xrow + j * 4);
#pragma unroll
    for (int j = 0; j < 4; ++j) br[j] = *(const uint4*)(Wrow + j * 8);
#pragma unroll
    for (int j2 = 0; j2 < 4; ++j2) {
        const float4 u = ar[j2 * 2], v = ar[j2 * 2 + 1];
        f16x8 h;
        h[0] = (_Float16)u.x; h[1] = (_Float16)u.y; h[2] = (_Float16)u.z; h[3] = (_Float16)u.w;
        h[4] = (_Float16)v.x; h[5] = (_Float16)v.y; h[6] = (_Float16)v.z; h[7] = (_Float16)v.w;
        int k0 = akq + j2 * 8;
        *(f16x8*)&lds_h[arow * 64 + (k0 ^ sw)] = h;
        *(uint4*)&lds_h[16384 + arow * 64 + (k0 ^ sw)] = br[j2];
    }
    __syncthreads();

    int cur = 0;
    for (int kt = 0; kt < 8; ++kt) {
        // issue next stage's global loads early (latency hidden under MFMA)
        if (kt < 7) {
#pragma unroll
            for (int j = 0; j < 8; ++j) ar[j] = *(const float4*)(Xrow + (kt + 1) * 64 + j * 4);
#pragma unroll
            for (int j = 0; j < 4; ++j) br[j] = *(const uint4*)(Wrow + (kt + 1) * 64 + j * 8);
        }
        // compute on buf `cur`
        const int bb = cur * 32768;
#pragma unroll
        for (int k32 = 0; k32 < 2; ++k32) {
            const int kb = k32 * 32 + ((lane >> 4) << 3);
            f16x8 bfr[4];
#pragma unroll
            for (int nt = 0; nt < 4; ++nt) {
                int col = wn * 64 + nt * 16 + (lane & 15);
                bfr[nt] = *(const f16x8*)&lds_h[bb + 16384 + col * 64 + (kb ^ ((col & 7) << 3))];
            }
#pragma unroll
            for (int rt = 0; rt < 8; ++rt) {
                int row = wm * 128 + rt * 16 + (lane & 15);
                f16x8 afr = *(const f16x8*)&lds_h[bb + row * 64 + (kb ^ ((row & 7) << 3))];
#pragma unroll
                for (int nt = 0; nt < 4; ++nt)
                    acc[rt][nt] = __builtin_amdgcn_mfma_f32_16x16x32_f16(afr, bfr[nt], acc[rt][nt], 0, 0, 0);
            }
        }
        // convert + write next stage into the other buffer
        if (kt < 7) {
            const int nb = (cur ^ 1) * 32768;
#pragma unroll
            for (int j2 = 0; j2 < 4; ++j2) {
                const float4 u = ar[j2 * 2], v = ar[j2 * 2 + 1];
                f16x8 h;
                h[0] = (_Float16)u.x; h[1] = (_Float16)u.y; h[2] = (_Float16)u.z; h[3] = (_Float16)u.w;
                h[4] = (_Float16)v.x; h[5] = (_Float16)v.y; h[6] = (_Float16)v.z; h[7] = (_Float16)v.w;
                int k0 = akq + j2 * 8;
                *(f16x8*)&lds_h[nb + arow * 64 + (k0 ^ sw)] = h;
                *(uint4*)&lds_h[nb + 16384 + arow * 64 + (k0 ^ sw)] = br[j2];
            }
        }
        __syncthreads();
        cur ^= 1;
    }

    // ---- epilogue ----
    float bias_l[4];
#pragma unroll
    for (int nt = 0; nt < 4; ++nt) bias_l[nt] = biasN[wn * 64 + nt * 16 + (lane & 15)];

    for (int pp = 0; pp < 2; ++pp) {
        // pass 1: waves owning this 128-row half write sigmoid(decisions) to LDS
        if (wm == pp) {
#pragma unroll
            for (int rt = 0; rt < 8; ++rt)
#pragma unroll
                for (int nt = 0; nt < 4; ++nt) {
                    int col = wn * 64 + nt * 16 + (lane & 15);
#pragma unroll
                    for (int reg = 0; reg < 4; ++reg) {
                        int row = rt * 16 + ((lane >> 4) << 2) + reg;
                        float z = acc[rt][nt][reg] + bias_l[nt];
                        float d = __builtin_amdgcn_rcpf(1.f + __expf(-z));
                        lds_f[row * 257 + col] = d;
                    }
                }
        }
        __syncthreads();
        // pass 2: 4 thread-groups x 128 rows; each group sums 16 trees
        {
            const int g = tid >> 7, row = tid & 127;
            float o0 = 0.f, o1 = 0.f;
#pragma unroll
            for (int ttl = 0; ttl < 16; ++ttl) {
                int t = g * 16 + ttl;
                const float* dp = lds_f + row * 257 + t * 4;
                float d0 = dp[0], d1 = dp[1], d2 = dp[2], d3 = dp[3];
                const float* abt = lds_f + AB_LDS + t * 10;
                float inv = __builtin_amdgcn_rcpf(4.f + d3 + 1e-8f);
                o0 += (abt[0] + d0 * abt[2] + d1 * abt[4] + d2 * abt[6] + d3 * abt[8]) * inv;
                o1 += (abt[1] + d0 * abt[3] + d1 * abt[5] + d2 * abt[7] + d3 * abt[9]) * inv;
            }
            lds_f[PART_LDS + (g * 128 + row) * 2 + 0] = o0;
            lds_f[PART_LDS + (g * 128 + row) * 2 + 1] = o1;
        }
        __syncthreads();
        if (tid < 256) {
            int r = tid >> 1, c = tid & 1;
            float s = 0.f;
#pragma unroll
            for (int g2 = 0; g2 < 4; ++g2) s += lds_f[PART_LDS + (g2 * 128 + r) * 2 + c];
            out[(size_t)(gr0 + pp * 128 + r) * 2 + c] = s;
        }
        if (pp == 0) __syncthreads();
    }
}

extern "C" void kernel_launch(void* const* d_in, const int* in_sizes, int n_in,
                              void* d_out, int out_size, void* d_ws, size_t ws_size,
                              hipStream_t stream) {
    const float* x  = (const float*)d_in[0];
    const float* tp = (const float*)d_in[1];
    const float* tw = (const float*)d_in[2];
    float* out = (float*)d_out;

    _Float16* Wh = (_Float16*)d_ws;
    float* biasN = (float*)((char*)d_ws + 262144);
    float* AB    = (float*)((char*)d_ws + 263168);

    (void)hipFuncSetAttribute((const void*)reinterpret_cast<const void*>(&main_kernel),
                              hipFuncAttributeMaxDynamicSharedMemorySize, 138240);

    prep_kernel<<<256, 128, 0, stream>>>(tp, tw, Wh, biasN, AB);
    main_kernel<<<256, 512, 138240, stream>>>(x, Wh, biasN, AB, out);
}

// Round 2
// 41.933 us; speedup vs baseline: 1.1525x; 1.1525x over previous
//
#include <hip/hip_runtime.h>
#include <stdint.h>

// Soft decision-tree ensemble, collapsed to:
//   out[b,c] = sum_t ( A'[t,c] + sum_{k<4} d[b,t,k]*B'[t,k,c] ) / (4 + d[b,t,3] + 1e-8)
//   d[b,t,k] = sigmoid( X[b,:] . W[t,k,:] + bias[t,k] ),  only internal nodes 0..3 matter.
// GEMM: 65536x512 @ 512x256 (fp16 MFMA), memory-bound on X (134 MB fp32, read once).
// Structure: 128x256 tile, BK=32, global_load_lds staging (X as f32, cvt at frag load),
// counted-vmcnt double-buffer (never drain), 2 blocks/CU.

#define KDIM 512
#define PPT 3607

typedef _Float16 f16x8 __attribute__((ext_vector_type(8)));
typedef float f32x4 __attribute__((ext_vector_type(4)));

// ws layout (bytes):
//   [0, 262144)       Wh   : _Float16 [256 cols][512 k]   (col = t*4 + node)
//   [262144, 263168)  biasN: float[256]
//   [263168, 265728)  AB   : float[64][10]  (A'c0,A'c1, B'n0c0,B'n0c1, ..., B'n3c1), w_t folded

__global__ __launch_bounds__(128) void prep_kernel(const float* __restrict__ p,
                                                   const float* __restrict__ tw,
                                                   _Float16* __restrict__ Wh,
                                                   float* __restrict__ biasN,
                                                   float* __restrict__ AB) {
    const int c = blockIdx.x;          // 0..255
    const int t = c >> 2, i = c & 3;
    const float* wsrc = p + t * PPT + i * KDIM;
    for (int k = threadIdx.x; k < KDIM; k += 128)
        Wh[c * KDIM + k] = (_Float16)wsrc[k];
    if (threadIdx.x == 0)
        biasN[c] = p[t * PPT + 7 * KDIM + i];
    if (threadIdx.x == 64 && c < 64) {
        const int tt = c;
        const float* lg = p + tt * PPT + 7 * 513;   // leaf logits, 8 x 2
        const float w = tw[tt];
        float ld[8][2];
#pragma unroll
        for (int j = 0; j < 8; ++j) {
            float a = lg[2 * j], b = lg[2 * j + 1];
            float m = fmaxf(a, b);
            float e0 = expf(a - m), e1 = expf(b - m);
            float s = e0 + e1;
            ld[j][0] = e0 / s; ld[j][1] = e1 / s;
        }
        float* o = AB + tt * 10;
#pragma unroll
        for (int cc = 0; cc < 2; ++cc) {
            o[0 + cc] = w * (ld[0][cc] + ld[2][cc] + ld[4][cc] + ld[6][cc]);
            o[2 + cc] = w * (ld[1][cc] - ld[2][cc]);
            o[4 + cc] = w * (ld[3][cc] - ld[4][cc]);
            o[6 + cc] = w * (ld[5][cc] - ld[6][cc]);
            o[8 + cc] = w * (ld[7][cc]);
        }
    }
}

// LDS map (73216 B / block, 2 blocks/CU):
//   staging buf b (b=0,1) at b*32768:
//     X f32 [128][32] at +0      (16384 B), col-swizzled: c' = c ^ ((row&7)<<2)   [4-f32 granule]
//     W f16 [256][32] at +16384  (16384 B), k-swizzled:   k' = k ^ (((col>>1)&3)<<3) [8-f16 granule]
//   epilogue overlay (loop-dead): d [64][260] f32 at 0 (66560 B)
//   AB coeffs at 66560 (2560 B);  partials [8][64][2] f32 at 69120 (4096 B)
#define BUF_STRIDE 32768
#define W_OFF 16384
#define EPI_STRIDE 260
#define AB_OFF 66560
#define PART_OFF 69120
#define LDS_BYTES 73216

__device__ __forceinline__ void gll16(const void* g, void* l) {
    __builtin_amdgcn_global_load_lds((const __attribute__((address_space(1))) uint32_t*)g,
                                     (__attribute__((address_space(3))) uint32_t*)l, 16, 0, 0);
}

__global__ __launch_bounds__(512, 4) void main_kernel(const float* __restrict__ X,
                                                      const _Float16* __restrict__ Wh,
                                                      const float* __restrict__ biasN,
                                                      const float* __restrict__ ABg,
                                                      float* __restrict__ out) {
    extern __shared__ char smem[];
    const int tid = threadIdx.x;
    const int lane = tid & 63;
    const int w = tid >> 6;          // wave 0..7
    const int wm = w >> 2;           // 0..1 : 64-row half
    const int wn = w & 3;            // 0..3 : 64-col quarter
    const int gr0 = blockIdx.x * 128;

    // preload folded leaf coefficients (region untouched by staging)
    {
        float* abl = (float*)(smem + AB_OFF);
        for (int i = tid; i < 640; i += 512) abl[i] = ABg[i];
    }
    asm volatile("s_waitcnt vmcnt(0)" ::: "memory");  // clean vmcnt slate before counted waits

    // ---- staging addresses (pre-swizzled global sources; linear gll dests) ----
    const float* srcX[2];
    const _Float16* srcW[2];
    int ldoX[2], ldoW[2];
#pragma unroll
    for (int i = 0; i < 2; ++i) {
        int rowX = i * 64 + w * 8 + (lane >> 3);              // 0..127
        int cX = ((lane & 7) << 2) ^ ((rowX & 7) << 2);       // inverse-swizzled source col
        srcX[i] = X + (size_t)(gr0 + rowX) * KDIM + cX;
        ldoX[i] = (i * 512 + w * 64 + lane) * 16;
        int colW = i * 128 + w * 16 + (lane >> 2);            // 0..255
        int kW = ((lane & 3) << 3) ^ (((colW >> 1) & 3) << 3);
        srcW[i] = Wh + (size_t)colW * KDIM + kW;
        ldoW[i] = W_OFF + (i * 512 + w * 64 + lane) * 16;
    }

#define STAGE(kt, b) do {                                   \
        char* _bb = smem + (b) * BUF_STRIDE;                \
        gll16(srcX[0] + (kt) * 32, _bb + ldoX[0]);          \
        gll16(srcX[1] + (kt) * 32, _bb + ldoX[1]);          \
        gll16(srcW[0] + (kt) * 32, _bb + ldoW[0]);          \
        gll16(srcW[1] + (kt) * 32, _bb + ldoW[1]);          \
    } while (0)

    f32x4 acc[4][4];
#pragma unroll
    for (int rt = 0; rt < 4; ++rt)
#pragma unroll
        for (int nt = 0; nt < 4; ++nt)
            acc[rt][nt] = (f32x4){0.f, 0.f, 0.f, 0.f};

    // fragment-read constants
    const int kb = (lane >> 4) << 3;              // 0,8,16,24
    const int swA = (lane & 7) << 2;              // = (row&7)<<2 for row = ..+(lane&15)
    const int swB = ((lane >> 1) & 3) << 3;       // = ((col>>1)&3)<<3 for col = ..+(lane&15)
    const int aRowBase = (wm * 64 + (lane & 15)) * 32;
    const int bColBase = (wn * 64 + (lane & 15)) * 32;

    STAGE(0, 0);

    for (int kt = 0; kt < 16; ++kt) {
        const int b = kt & 1;
        __builtin_amdgcn_s_barrier();              // prior reads of buf b^1 complete -> safe to refill
        if (kt < 15) {
            STAGE(kt + 1, b ^ 1);
            asm volatile("s_waitcnt vmcnt(4)" ::: "memory");   // own tile-kt loads landed; kt+1 stays in flight
        } else {
            asm volatile("s_waitcnt vmcnt(0)" ::: "memory");
        }
        __builtin_amdgcn_s_barrier();              // all waves' tile-kt loads landed
        asm volatile("" ::: "memory");

        const float* Xl = (const float*)(smem + b * BUF_STRIDE);
        const _Float16* Wl = (const _Float16*)(smem + b * BUF_STRIDE + W_OFF);

        f16x8 bfr[4];
#pragma unroll
        for (int nt = 0; nt < 4; ++nt)
            bfr[nt] = *(const f16x8*)&Wl[bColBase + nt * 512 + (kb ^ swB)];
#pragma unroll
        for (int rt = 0; rt < 4; ++rt) {
            float4 a0 = *(const float4*)&Xl[aRowBase + rt * 512 + (kb ^ swA)];
            float4 a1 = *(const float4*)&Xl[aRowBase + rt * 512 + ((kb + 4) ^ swA)];
            f16x8 af;
            af[0] = (_Float16)a0.x; af[1] = (_Float16)a0.y;
            af[2] = (_Float16)a0.z; af[3] = (_Float16)a0.w;
            af[4] = (_Float16)a1.x; af[5] = (_Float16)a1.y;
            af[6] = (_Float16)a1.z; af[7] = (_Float16)a1.w;
#pragma unroll
            for (int nt = 0; nt < 4; ++nt)
                acc[rt][nt] = __builtin_amdgcn_mfma_f32_16x16x32_f16(af, bfr[nt], acc[rt][nt], 0, 0, 0);
        }
    }

    // ---- epilogue: 2 passes of 64 rows, transpose via LDS overlay ----
    __syncthreads();   // all compute reads done before overlaying staging region

    for (int p = 0; p < 2; ++p) {
        if (wm == p) {
            float bl[4];
#pragma unroll
            for (int nt = 0; nt < 4; ++nt) bl[nt] = biasN[wn * 64 + nt * 16 + (lane & 15)];
            float* ep = (float*)smem;
#pragma unroll
            for (int rt = 0; rt < 4; ++rt)
#pragma unroll
                for (int nt = 0; nt < 4; ++nt) {
                    const int col = wn * 64 + nt * 16 + (lane & 15);
#pragma unroll
                    for (int reg = 0; reg < 4; ++reg) {
                        const int rowl = rt * 16 + ((lane >> 4) << 2) + reg;
                        float z = acc[rt][nt][reg] + bl[nt];
                        ep[rowl * EPI_STRIDE + col] = __builtin_amdgcn_rcpf(1.f + __expf(-z));
                    }
                }
        }
        __syncthreads();
        {   // all 8 waves: wave w sums trees w*8..w*8+7 for all 64 rows (lane = row)
            const float* ep = (const float*)smem;
            const float* abl = (const float*)(smem + AB_OFF);
            float* pb = (float*)(smem + PART_OFF);
            const int r = lane;
            float s0 = 0.f, s1 = 0.f;
#pragma unroll
            for (int j = 0; j < 8; ++j) {
                const int t = w * 8 + j;
                float4 dv = *(const float4*)&ep[r * EPI_STRIDE + t * 4];
                const float* abt = &abl[t * 10];
                float inv = __builtin_amdgcn_rcpf(4.f + dv.w + 1e-8f);
                s0 += (abt[0] + dv.x * abt[2] + dv.y * abt[4] + dv.z * abt[6] + dv.w * abt[8]) * inv;
                s1 += (abt[1] + dv.x * abt[3] + dv.y * abt[5] + dv.z * abt[7] + dv.w * abt[9]) * inv;
            }
            pb[(w * 64 + r) * 2 + 0] = s0;
            pb[(w * 64 + r) * 2 + 1] = s1;
        }
        __syncthreads();
        if (tid < 128) {
            const float* pb = (const float*)(smem + PART_OFF);
            const int r = tid >> 1, c = tid & 1;
            float s = 0.f;
#pragma unroll
            for (int g = 0; g < 8; ++g) s += pb[(g * 64 + r) * 2 + c];
            out[(size_t)(gr0 + p * 64 + r) * 2 + c] = s;
        }
        if (p == 0) __syncthreads();
    }
#undef STAGE
}

extern "C" void kernel_launch(void* const* d_in, const int* in_sizes, int n_in,
                              void* d_out, int out_size, void* d_ws, size_t ws_size,
                              hipStream_t stream) {
    const float* x  = (const float*)d_in[0];
    const float* tp = (const float*)d_in[1];
    const float* tw = (const float*)d_in[2];
    float* out = (float*)d_out;

    _Float16* Wh = (_Float16*)d_ws;
    float* biasN = (float*)((char*)d_ws + 262144);
    float* AB    = (float*)((char*)d_ws + 263168);

    (void)hipFuncSetAttribute((const void*)reinterpret_cast<const void*>(&main_kernel),
                              hipFuncAttributeMaxDynamicSharedMemorySize, LDS_BYTES);

    prep_kernel<<<256, 128, 0, stream>>>(tp, tw, Wh, biasN, AB);
    main_kernel<<<512, 512, LDS_BYTES, stream>>>(x, Wh, biasN, AB, out);
}